// Round 30
// baseline (111.279 us; speedup 1.0000x reference)
//
#include <hip/hip_runtime.h>
#include <math.h>

#define B_ 256
#define S_ 50
#define K_ 20
#define D_ 128
#define G3 384          // 3*D
#define M_  (B_ * S_)   // 12800 (b,s) rows
#define GROWS 32        // batch rows per GRU block (v15: 16 -> 32)
#define KT 4            // k-tiles (32 wide): 128

typedef __attribute__((ext_vector_type(8))) short bf16x8;
typedef __attribute__((ext_vector_type(4))) float f32x4;

__device__ inline unsigned short bf16_rne(float f) {
    unsigned u = __float_as_uint(f);
    return (unsigned short)((u + 0x7fffu + ((u >> 16) & 1u)) >> 16);
}

#define WG_SYNC_LDS() do { \
    __builtin_amdgcn_sched_barrier(0); \
    asm volatile("s_waitcnt lgkmcnt(0)" ::: "memory"); \
    __builtin_amdgcn_s_barrier(); \
    __builtin_amdgcn_sched_barrier(0); \
} while (0)

// ---------------------------------------------------------------------------
// Kernel P v2 (R26 proven): basket pooling, float2/lane, 3200 blocks.
// ---------------------------------------------------------------------------
__global__ __launch_bounds__(256) void pool_kernel(
    const int* __restrict__ items, const int* __restrict__ basket_len,
    const int* __restrict__ lengths, const float* __restrict__ encode,
    unsigned short* __restrict__ pooled_bf)
{
    const int tid = threadIdx.x;
    const int sub = tid >> 6;          // 0..3: row within block
    const int d2  = tid & 63;          // float2 index within row
    const int m   = blockIdx.x * 4 + sub;
    const int b   = m / S_;
    const int s   = m % S_;
    const int len = lengths[b];

    float px = 0.f, py = 0.f;
    if (s < len) {
        const int  blen = basket_len[m];
        const int* it   = items + m * K_;
        #pragma unroll 4
        for (int k = 0; k < blen; ++k) {
            float2 e = *(const float2*)(encode + (long)it[k] * D_ + d2 * 2);
            px += e.x; py += e.y;
        }
        px /= (float)blen; py /= (float)blen;
    }
    unsigned short lo = bf16_rne(px), hi = bf16_rne(py);
    *(unsigned*)(pooled_bf + m * D_ + d2 * 2) = (unsigned)lo | ((unsigned)hi << 16);
}

// ---------------------------------------------------------------------------
// Kernel G v4 (R24 proven): MFMA GEMM with inline w_ih f32->bf16 staging.
// ---------------------------------------------------------------------------
__global__ __launch_bounds__(256) void gx_gemm_mfma(
    const unsigned short* __restrict__ pooled_bf,
    const float* __restrict__ w_ih,
    const float* __restrict__ b_ih, const float* __restrict__ b_hh,
    float* __restrict__ gx)
{
    __shared__ unsigned short Al[128 * 128];   // [m][k] swizzled, 32KB
    __shared__ unsigned short Bl[128 * 128];   // [n][k] swizzled, 32KB

    const int tid  = threadIdx.x;
    const int bm   = blockIdx.x % 100;
    const int bn   = blockIdx.x / 100;         // 0..2
    const int m0   = bm * 128;
    const int n0   = bn * 128;
    const int lane = tid & 63;
    const int wv   = tid >> 6;                 // 0..3
    const int frow = lane & 15;
    const int fhi  = lane >> 4;
    const int mh   = (wv & 1) * 64;
    const int nh   = (wv >> 1) * 64;

    #pragma unroll
    for (int i = 0; i < 8; ++i) {
        int idx = tid + i * 256;               // 0..2047
        int row = idx >> 4, c16 = idx & 15;
        int dst = (row * 256 + c16 * 16) ^ ((row & 7) << 4);
        *(bf16x8*)((char*)Al + dst) =
            *(const bf16x8*)(pooled_bf + (long)(m0 + row) * D_ + c16 * 8);
        const float* wp = w_ih + (long)(n0 + row) * D_ + c16 * 8;
        bf16x8 v;
        #pragma unroll
        for (int j = 0; j < 8; ++j) v[j] = (short)bf16_rne(wp[j]);
        *(bf16x8*)((char*)Bl + dst) = v;
    }
    __syncthreads();

    bf16x8 af[4][KT], bfr[4][KT];
    #pragma unroll
    for (int t = 0; t < 4; ++t) {
        #pragma unroll
        for (int kt = 0; kt < KT; ++kt) {
            int ra = mh + t * 16 + frow;
            int oa = (ra * 256 + kt * 64 + fhi * 16) ^ ((ra & 7) << 4);
            af[t][kt] = *(const bf16x8*)((const char*)Al + oa);
            int rb = nh + t * 16 + frow;
            int ob = (rb * 256 + kt * 64 + fhi * 16) ^ ((rb & 7) << 4);
            bfr[t][kt] = *(const bf16x8*)((const char*)Bl + ob);
        }
    }

    f32x4 acc[4][4];
    #pragma unroll
    for (int mt = 0; mt < 4; ++mt)
        #pragma unroll
        for (int nt = 0; nt < 4; ++nt) {
            f32x4 c = {0.f, 0.f, 0.f, 0.f};
            #pragma unroll
            for (int kt = 0; kt < KT; ++kt)
                c = __builtin_amdgcn_mfma_f32_16x16x32_bf16(af[mt][kt], bfr[nt][kt], c, 0, 0, 0);
            acc[mt][nt] = c;
        }

    float bias[4];
    #pragma unroll
    for (int nt = 0; nt < 4; ++nt) {
        int n = n0 + nh + nt * 16 + frow;
        bias[nt] = b_ih[n] + (n < 2 * D_ ? b_hh[n] : 0.f);   // fold r/z only
    }

    #pragma unroll
    for (int mt = 0; mt < 4; ++mt) {
        #pragma unroll
        for (int nt = 0; nt < 4; ++nt) {
            int n = n0 + nh + nt * 16 + frow;
            #pragma unroll
            for (int r = 0; r < 4; ++r) {
                int row = m0 + mh + mt * 16 + fhi * 4 + r;
                gx[(long)row * G3 + n] = acc[mt][nt][r] + bias[nt];
            }
        }
    }
}

// ---------------------------------------------------------------------------
// Kernel B v15: v14 with GROWS=32, 1024 thr (16 waves = 4 waves/SIMD).
// Per-lane work per step IDENTICAL to v14 (4 rows x 1 dim); only change is
// 2x TLP to hide the gate phase's serial exp/rcp chains (~100+cyc each),
// which 2 waves/SIMD could not cover. Pre-commit: flat => step floor real.
// Wave wv: m-tile = wv>>3 (rows mt*16+fhi*4+r), dims = (wv&7)*16+frow.
// ---------------------------------------------------------------------------
__global__ __launch_bounds__(1024, 1) void gru_mfma_kernel(
    const int* __restrict__ lengths, const float* __restrict__ w_hh,
    const float* __restrict__ b_hh, const float* __restrict__ h0,
    const float* __restrict__ gx, float* __restrict__ out)
{
    const int b0   = blockIdx.x * GROWS;
    const int tid  = threadIdx.x;
    const int lane = tid & 63;
    const int wv   = tid >> 6;          // 0..15
    const int frow = lane & 15;
    const int fhi  = lane >> 4;
    const int dim  = (wv & 7) * 16 + frow;   // this lane's hidden dim
    const int mt   = wv >> 3;                // 0/1: which 16-row half

    __shared__ unsigned short hb[2][GROWS * D_];

    bf16x8 wf[3][KT];
    #pragma unroll
    for (int g = 0; g < 3; ++g) {
        #pragma unroll
        for (int kt = 0; kt < KT; ++kt) {
            const float* wp = w_hh + (g * D_ + dim) * D_ + kt * 32 + fhi * 8;
            bf16x8 v;
            #pragma unroll
            for (int j = 0; j < 8; ++j) v[j] = (short)bf16_rne(wp[j]);
            wf[g][kt] = v;
        }
    }

    const float bhn_s = b_hh[2 * D_ + dim];

    int   mylen[4];
    float hp[4];
    #pragma unroll
    for (int r = 0; r < 4; ++r) {
        int row = mt * 16 + fhi * 4 + r;           // 0..31
        mylen[r] = lengths[b0 + row];
        hp[r]    = h0[(long)(b0 + row) * D_ + dim];
        int wb = (row * 256 + dim * 2) ^ ((row & 7) << 4);
        *(unsigned short*)((char*)hb[0] + wb) = bf16_rne(hp[r]);
    }
    const int lenmax = lengths[b0];
    __syncthreads();

    float* ys = out;
    float* hu = out + (long)B_ * S_ * D_;

    const long gxrow[4] = {
        (long)(b0 + mt * 16 + fhi * 4 + 0) * S_, (long)(b0 + mt * 16 + fhi * 4 + 1) * S_,
        (long)(b0 + mt * 16 + fhi * 4 + 2) * S_, (long)(b0 + mt * 16 + fhi * 4 + 3) * S_ };

    #define GSTEP(s, CUR, NXT, PP) { \
        const int sn = ((s) + 1 < lenmax) ? (s) + 1 : lenmax - 1; \
        _Pragma("unroll") \
        for (int g = 0; g < 3; ++g) \
            _Pragma("unroll") \
            for (int r = 0; r < 4; ++r) \
                NXT[g][r] = gx[(gxrow[r] + sn) * G3 + g * 128 + dim]; \
        bf16x8 ah[KT]; \
        _Pragma("unroll") \
        for (int kt = 0; kt < KT; ++kt) { \
            int ar = mt * 16 + frow; \
            int ab = (ar * 256 + kt * 64 + fhi * 16) ^ ((ar & 7) << 4); \
            ah[kt] = *(const bf16x8*)((const char*)hb[PP] + ab); \
        } \
        f32x4 cr = {0.f,0.f,0.f,0.f}, cz = {0.f,0.f,0.f,0.f}, cn = {0.f,0.f,0.f,0.f}; \
        _Pragma("unroll") \
        for (int kt = 0; kt < KT; ++kt) { \
            cr = __builtin_amdgcn_mfma_f32_16x16x32_bf16(ah[kt], wf[0][kt], cr, 0, 0, 0); \
            cz = __builtin_amdgcn_mfma_f32_16x16x32_bf16(ah[kt], wf[1][kt], cz, 0, 0, 0); \
            cn = __builtin_amdgcn_mfma_f32_16x16x32_bf16(ah[kt], wf[2][kt], cn, 0, 0, 0); \
        } \
        _Pragma("unroll") \
        for (int r = 0; r < 4; ++r) { \
            const int row = mt * 16 + fhi * 4 + r; \
            const bool act = (s) < mylen[r]; \
            float a  = __expf(-(CUR[0][r] + cr[r])); \
            float bb = __expf(-(CUR[1][r] + cz[r])); \
            float inv = __builtin_amdgcn_rcpf((1.f + a) * (1.f + bb)); \
            float rg = (1.f + bb) * inv; \
            float zg = (1.f + a) * inv; \
            float xx = fmaf(rg, cn[r] + bhn_s, CUR[2][r]); \
            float tt = __expf(2.f * xx); \
            float ng = fmaf(-2.f, __builtin_amdgcn_rcpf(1.f + tt), 1.f); \
            float hn = fmaf(zg, hp[r] - ng, ng); \
            if (act) { \
                ys[(gxrow[r] + (s)) * D_ + dim] = hn; \
                hp[r] = hn; \
            } \
            int wb = (row * 256 + dim * 2) ^ ((row & 7) << 4); \
            *(unsigned short*)((char*)hb[(PP) ^ 1] + wb) = bf16_rne(hp[r]); \
        } \
        WG_SYNC_LDS(); \
    }

    float curA[3][4], curB[3][4];
    #pragma unroll
    for (int g = 0; g < 3; ++g)
        #pragma unroll
        for (int r = 0; r < 4; ++r)
            curA[g][r] = gx[(gxrow[r] + 0) * G3 + g * 128 + dim];

    int s = 0, pp = 0;
    while (s < lenmax) {
        GSTEP(s, curA, curB, pp);
        ++s; pp ^= 1;
        if (s >= lenmax) break;
        GSTEP(s, curB, curA, pp);
        ++s; pp ^= 1;
    }
    #undef GSTEP

    #pragma unroll
    for (int r = 0; r < 4; ++r) {
        const int row = mt * 16 + fhi * 4 + r;
        hu[(long)(b0 + row) * D_ + dim] = hp[r];
        for (int t = mylen[r]; t < S_; ++t)
            ys[((long)(b0 + row) * S_ + t) * D_ + dim] = 0.f;
    }
}

extern "C" void kernel_launch(void* const* d_in, const int* in_sizes, int n_in,
                              void* d_out, int out_size, void* d_ws, size_t ws_size,
                              hipStream_t stream) {
    const int*   items      = (const int*)d_in[0];
    const int*   basket_len = (const int*)d_in[1];
    const int*   lengths    = (const int*)d_in[2];
    const float* encode     = (const float*)d_in[3];
    const float* w_ih       = (const float*)d_in[4];
    const float* w_hh       = (const float*)d_in[5];
    const float* b_ih       = (const float*)d_in[6];
    const float* b_hh       = (const float*)d_in[7];
    const float* h0         = (const float*)d_in[8];
    float* out = (float*)d_out;

    float*          gx        = (float*)d_ws;                    // 19.66 MB
    unsigned short* pooled_bf = (unsigned short*)(gx + (long)M_ * G3);  // 3.28 MB

    pool_kernel<<<M_ / 4, 256, 0, stream>>>(
        items, basket_len, lengths, encode, pooled_bf);
    gx_gemm_mfma<<<300, 256, 0, stream>>>(
        pooled_bf, w_ih, b_ih, b_hh, gx);
    gru_mfma_kernel<<<B_ / GROWS, 1024, 0, stream>>>(
        lengths, w_hh, b_hh, h0, gx, out);
}

// Round 31
// 71.252 us; speedup vs baseline: 1.5618x; 1.5618x over previous
//
#include <hip/hip_runtime.h>
#include <math.h>

#define B_ 256
#define S_ 50
#define K_ 20
#define D_ 128
#define G3 384          // 3*D
#define M_  (B_ * S_)   // 12800 (b,s) rows
#define GROWS 16        // batch rows per GRU block (R30: 32 regressed, reverted)
#define KT 4            // k-tiles (32 wide): 128

typedef __attribute__((ext_vector_type(8))) short bf16x8;
typedef __attribute__((ext_vector_type(4))) float f32x4;

__device__ inline unsigned short bf16_rne(float f) {
    unsigned u = __float_as_uint(f);
    return (unsigned short)((u + 0x7fffu + ((u >> 16) & 1u)) >> 16);
}

#define WG_SYNC_LDS() do { \
    __builtin_amdgcn_sched_barrier(0); \
    asm volatile("s_waitcnt lgkmcnt(0)" ::: "memory"); \
    __builtin_amdgcn_s_barrier(); \
    __builtin_amdgcn_sched_barrier(0); \
} while (0)

// ---------------------------------------------------------------------------
// Kernel P v2 (R26 proven): basket pooling, float2/lane, 3200 blocks.
// ---------------------------------------------------------------------------
__global__ __launch_bounds__(256) void pool_kernel(
    const int* __restrict__ items, const int* __restrict__ basket_len,
    const int* __restrict__ lengths, const float* __restrict__ encode,
    unsigned short* __restrict__ pooled_bf)
{
    const int tid = threadIdx.x;
    const int sub = tid >> 6;          // 0..3: row within block
    const int d2  = tid & 63;          // float2 index within row
    const int m   = blockIdx.x * 4 + sub;
    const int b   = m / S_;
    const int s   = m % S_;
    const int len = lengths[b];

    float px = 0.f, py = 0.f;
    if (s < len) {
        const int  blen = basket_len[m];
        const int* it   = items + m * K_;
        #pragma unroll 4
        for (int k = 0; k < blen; ++k) {
            float2 e = *(const float2*)(encode + (long)it[k] * D_ + d2 * 2);
            px += e.x; py += e.y;
        }
        px /= (float)blen; py /= (float)blen;
    }
    unsigned short lo = bf16_rne(px), hi = bf16_rne(py);
    *(unsigned*)(pooled_bf + m * D_ + d2 * 2) = (unsigned)lo | ((unsigned)hi << 16);
}

// ---------------------------------------------------------------------------
// Kernel G v4 (R24 proven): MFMA GEMM with inline w_ih f32->bf16 staging.
// ---------------------------------------------------------------------------
__global__ __launch_bounds__(256) void gx_gemm_mfma(
    const unsigned short* __restrict__ pooled_bf,
    const float* __restrict__ w_ih,
    const float* __restrict__ b_ih, const float* __restrict__ b_hh,
    float* __restrict__ gx)
{
    __shared__ unsigned short Al[128 * 128];   // [m][k] swizzled, 32KB
    __shared__ unsigned short Bl[128 * 128];   // [n][k] swizzled, 32KB

    const int tid  = threadIdx.x;
    const int bm   = blockIdx.x % 100;
    const int bn   = blockIdx.x / 100;         // 0..2
    const int m0   = bm * 128;
    const int n0   = bn * 128;
    const int lane = tid & 63;
    const int wv   = tid >> 6;                 // 0..3
    const int frow = lane & 15;
    const int fhi  = lane >> 4;
    const int mh   = (wv & 1) * 64;
    const int nh   = (wv >> 1) * 64;

    #pragma unroll
    for (int i = 0; i < 8; ++i) {
        int idx = tid + i * 256;               // 0..2047
        int row = idx >> 4, c16 = idx & 15;
        int dst = (row * 256 + c16 * 16) ^ ((row & 7) << 4);
        *(bf16x8*)((char*)Al + dst) =
            *(const bf16x8*)(pooled_bf + (long)(m0 + row) * D_ + c16 * 8);
        const float* wp = w_ih + (long)(n0 + row) * D_ + c16 * 8;
        bf16x8 v;
        #pragma unroll
        for (int j = 0; j < 8; ++j) v[j] = (short)bf16_rne(wp[j]);
        *(bf16x8*)((char*)Bl + dst) = v;
    }
    __syncthreads();

    bf16x8 af[4][KT], bfr[4][KT];
    #pragma unroll
    for (int t = 0; t < 4; ++t) {
        #pragma unroll
        for (int kt = 0; kt < KT; ++kt) {
            int ra = mh + t * 16 + frow;
            int oa = (ra * 256 + kt * 64 + fhi * 16) ^ ((ra & 7) << 4);
            af[t][kt] = *(const bf16x8*)((const char*)Al + oa);
            int rb = nh + t * 16 + frow;
            int ob = (rb * 256 + kt * 64 + fhi * 16) ^ ((rb & 7) << 4);
            bfr[t][kt] = *(const bf16x8*)((const char*)Bl + ob);
        }
    }

    f32x4 acc[4][4];
    #pragma unroll
    for (int mt = 0; mt < 4; ++mt)
        #pragma unroll
        for (int nt = 0; nt < 4; ++nt) {
            f32x4 c = {0.f, 0.f, 0.f, 0.f};
            #pragma unroll
            for (int kt = 0; kt < KT; ++kt)
                c = __builtin_amdgcn_mfma_f32_16x16x32_bf16(af[mt][kt], bfr[nt][kt], c, 0, 0, 0);
            acc[mt][nt] = c;
        }

    float bias[4];
    #pragma unroll
    for (int nt = 0; nt < 4; ++nt) {
        int n = n0 + nh + nt * 16 + frow;
        bias[nt] = b_ih[n] + (n < 2 * D_ ? b_hh[n] : 0.f);   // fold r/z only
    }

    #pragma unroll
    for (int mt = 0; mt < 4; ++mt) {
        #pragma unroll
        for (int nt = 0; nt < 4; ++nt) {
            int n = n0 + nh + nt * 16 + frow;
            #pragma unroll
            for (int r = 0; r < 4; ++r) {
                int row = m0 + mh + mt * 16 + fhi * 4 + r;
                gx[(long)row * G3 + n] = acc[mt][nt][r] + bias[nt];
            }
        }
    }
}

// ---------------------------------------------------------------------------
// Kernel B v14 (R25/R26 proven, 49.9us): gates-in-registers MFMA GRU,
// LDS-only barrier, distance-1 named double buffer, lean gates. Structural
// plateau confirmed by 6 probes (v11 depth-2, v12 relayout, v13 fusion,
// v15 2x-TLP all regressed) — final config.
// ---------------------------------------------------------------------------
__global__ __launch_bounds__(512, 1) void gru_mfma_kernel(
    const int* __restrict__ lengths, const float* __restrict__ w_hh,
    const float* __restrict__ b_hh, const float* __restrict__ h0,
    const float* __restrict__ gx, float* __restrict__ out)
{
    const int b0   = blockIdx.x * GROWS;
    const int tid  = threadIdx.x;
    const int lane = tid & 63;
    const int wv   = tid >> 6;
    const int frow = lane & 15;
    const int fhi  = lane >> 4;
    const int dim  = wv * 16 + frow;

    __shared__ unsigned short hb[2][GROWS * D_];

    bf16x8 wf[3][KT];
    #pragma unroll
    for (int g = 0; g < 3; ++g) {
        #pragma unroll
        for (int kt = 0; kt < KT; ++kt) {
            const float* wp = w_hh + (g * D_ + dim) * D_ + kt * 32 + fhi * 8;
            bf16x8 v;
            #pragma unroll
            for (int j = 0; j < 8; ++j) v[j] = (short)bf16_rne(wp[j]);
            wf[g][kt] = v;
        }
    }

    const float bhn_s = b_hh[2 * D_ + dim];

    int   mylen[4];
    float hp[4];
    #pragma unroll
    for (int r = 0; r < 4; ++r) {
        int row = fhi * 4 + r;
        mylen[r] = lengths[b0 + row];
        hp[r]    = h0[(long)(b0 + row) * D_ + dim];
        int wb = (row * 256 + dim * 2) ^ ((row & 7) << 4);
        *(unsigned short*)((char*)hb[0] + wb) = bf16_rne(hp[r]);
    }
    const int lenmax = lengths[b0];
    __syncthreads();

    float* ys = out;
    float* hu = out + (long)B_ * S_ * D_;

    const long gxrow[4] = {
        (long)(b0 + fhi * 4 + 0) * S_, (long)(b0 + fhi * 4 + 1) * S_,
        (long)(b0 + fhi * 4 + 2) * S_, (long)(b0 + fhi * 4 + 3) * S_ };

    #define GSTEP(s, CUR, NXT, PP) { \
        const int sn = ((s) + 1 < lenmax) ? (s) + 1 : lenmax - 1; \
        _Pragma("unroll") \
        for (int g = 0; g < 3; ++g) \
            _Pragma("unroll") \
            for (int r = 0; r < 4; ++r) \
                NXT[g][r] = gx[(gxrow[r] + sn) * G3 + g * 128 + dim]; \
        bf16x8 ah[KT]; \
        _Pragma("unroll") \
        for (int kt = 0; kt < KT; ++kt) { \
            int ab = (frow * 256 + kt * 64 + fhi * 16) ^ ((frow & 7) << 4); \
            ah[kt] = *(const bf16x8*)((const char*)hb[PP] + ab); \
        } \
        f32x4 cr = {0.f,0.f,0.f,0.f}, cz = {0.f,0.f,0.f,0.f}, cn = {0.f,0.f,0.f,0.f}; \
        _Pragma("unroll") \
        for (int kt = 0; kt < KT; ++kt) { \
            cr = __builtin_amdgcn_mfma_f32_16x16x32_bf16(ah[kt], wf[0][kt], cr, 0, 0, 0); \
            cz = __builtin_amdgcn_mfma_f32_16x16x32_bf16(ah[kt], wf[1][kt], cz, 0, 0, 0); \
            cn = __builtin_amdgcn_mfma_f32_16x16x32_bf16(ah[kt], wf[2][kt], cn, 0, 0, 0); \
        } \
        _Pragma("unroll") \
        for (int r = 0; r < 4; ++r) { \
            const int row = fhi * 4 + r; \
            const bool act = (s) < mylen[r]; \
            float a  = __expf(-(CUR[0][r] + cr[r])); \
            float bb = __expf(-(CUR[1][r] + cz[r])); \
            float inv = __builtin_amdgcn_rcpf((1.f + a) * (1.f + bb)); \
            float rg = (1.f + bb) * inv; \
            float zg = (1.f + a) * inv; \
            float xx = fmaf(rg, cn[r] + bhn_s, CUR[2][r]); \
            float tt = __expf(2.f * xx); \
            float ng = fmaf(-2.f, __builtin_amdgcn_rcpf(1.f + tt), 1.f); \
            float hn = fmaf(zg, hp[r] - ng, ng); \
            if (act) { \
                ys[(gxrow[r] + (s)) * D_ + dim] = hn; \
                hp[r] = hn; \
            } \
            int wb = (row * 256 + dim * 2) ^ ((row & 7) << 4); \
            *(unsigned short*)((char*)hb[(PP) ^ 1] + wb) = bf16_rne(hp[r]); \
        } \
        WG_SYNC_LDS(); \
    }

    float curA[3][4], curB[3][4];
    #pragma unroll
    for (int g = 0; g < 3; ++g)
        #pragma unroll
        for (int r = 0; r < 4; ++r)
            curA[g][r] = gx[(gxrow[r] + 0) * G3 + g * 128 + dim];

    int s = 0, pp = 0;
    while (s < lenmax) {
        GSTEP(s, curA, curB, pp);
        ++s; pp ^= 1;
        if (s >= lenmax) break;
        GSTEP(s, curB, curA, pp);
        ++s; pp ^= 1;
    }
    #undef GSTEP

    #pragma unroll
    for (int r = 0; r < 4; ++r) {
        const int row = fhi * 4 + r;
        hu[(long)(b0 + row) * D_ + dim] = hp[r];
        for (int t = mylen[r]; t < S_; ++t)
            ys[((long)(b0 + row) * S_ + t) * D_ + dim] = 0.f;
    }
}

extern "C" void kernel_launch(void* const* d_in, const int* in_sizes, int n_in,
                              void* d_out, int out_size, void* d_ws, size_t ws_size,
                              hipStream_t stream) {
    const int*   items      = (const int*)d_in[0];
    const int*   basket_len = (const int*)d_in[1];
    const int*   lengths    = (const int*)d_in[2];
    const float* encode     = (const float*)d_in[3];
    const float* w_ih       = (const float*)d_in[4];
    const float* w_hh       = (const float*)d_in[5];
    const float* b_ih       = (const float*)d_in[6];
    const float* b_hh       = (const float*)d_in[7];
    const float* h0         = (const float*)d_in[8];
    float* out = (float*)d_out;

    float*          gx        = (float*)d_ws;                    // 19.66 MB
    unsigned short* pooled_bf = (unsigned short*)(gx + (long)M_ * G3);  // 3.28 MB

    pool_kernel<<<M_ / 4, 256, 0, stream>>>(
        items, basket_len, lengths, encode, pooled_bf);
    gx_gemm_mfma<<<300, 256, 0, stream>>>(
        pooled_bf, w_ih, b_ih, b_hh, gx);
    gru_mfma_kernel<<<B_ / GROWS, 512, 0, stream>>>(
        lengths, w_hh, b_hh, h0, gx, out);
}